// Round 3
// baseline (278.649 us; speedup 1.0000x reference)
//
#include <hip/hip_runtime.h>
#include <hip/hip_bf16.h>
#include <stdint.h>
#include <stddef.h>

// ---------------------------------------------------------------------------
// NonLocalBlock2D: B=8, C=256, H=W=64 (N=4096), CI=128
// out = x + Wout * softmax( (theta(x)^T phi(x)) * sqrt(CI) ) * g(x)
// Split-fp32 (bf16 hi+lo, 3-MFMA) upstream of softmax; plain bf16 after.
// V stored transposed [b][ci][n] so attention stages it conflict-free.
// k_attn: 32 q/wave, double-buffered LDS, reg-staged prefetch, 1 barrier/iter.
// ---------------------------------------------------------------------------

typedef __bf16 bf16;
typedef __attribute__((ext_vector_type(8))) __bf16 bf16x8;
typedef __attribute__((ext_vector_type(4))) __bf16 bf16x4;
typedef __attribute__((ext_vector_type(4))) float  f32x4;
typedef __attribute__((ext_vector_type(4))) int    i32x4;

#define MFMA16(a, b, c) __builtin_amdgcn_mfma_f32_16x16x32_bf16((a), (b), (c), 0, 0, 0)

constexpr int NB  = 8;
constexpr int NC  = 256;
constexpr int NN  = 4096;
constexpr int NCI = 128;
constexpr size_t NEL = (size_t)NB * NN * NCI;

// ---------------------------------------------------------------------------
// Kernel 1: projections (unchanged from round 2).
// ---------------------------------------------------------------------------
__global__ __launch_bounds__(256) void k_proj(
    const float* __restrict__ x,
    const float* __restrict__ wt, const float* __restrict__ bt,
    const float* __restrict__ wp, const float* __restrict__ bp,
    const float* __restrict__ wg, const float* __restrict__ bg,
    bf16* __restrict__ qh, bf16* __restrict__ ql,
    bf16* __restrict__ kh, bf16* __restrict__ kl,
    bf16* __restrict__ vv)
{
    const int nt  = blockIdx.x;      // 0..63
    const int pj  = blockIdx.y;      // 0..2
    const int b   = blockIdx.z;      // 0..7
    const int tid = threadIdx.x;
    const int wv  = tid >> 6;
    const int ln  = tid & 63;
    const int lg  = ln >> 4;
    const int lq  = ln & 15;

    const float* W;
    const float* bias;
    if (pj == 0)      { W = wt; bias = bt; }
    else if (pj == 1) { W = wp; bias = bp; }
    else              { W = wg; bias = bg; }
    const bool split = (pj != 2);

    __shared__ char lds[49152];
    char* Ah = lds;            // [64 n][64 c] bf16 hi, swizzled
    char* Al = lds + 8192;
    char* Wh = lds + 16384;    // [128 i][64 c] bf16 hi, swizzled
    char* Wl = lds + 32768;

    f32x4 acc[8];
#pragma unroll
    for (int j = 0; j < 8; ++j) acc[j] = f32x4{0.f, 0.f, 0.f, 0.f};

    const int n0 = nt * 64;

    for (int c0 = 0; c0 < NC; c0 += 64) {
        __syncthreads();
        // stage A: x[b, c0+cc, n0+nn] -> Ah/Al[nn][cc] (transpose + split)
#pragma unroll
        for (int p = 0; p < 4; ++p) {
            int cc = p * 16 + (tid >> 4);
            int nn = (tid & 15) * 4;
            f32x4 xv = *(const f32x4*)(x + ((size_t)b * NC + (c0 + cc)) * NN + n0 + nn);
#pragma unroll
            for (int e = 0; e < 4; ++e) {
                float f = xv[e];
                bf16 h = (bf16)f;
                int row = nn + e;
                int off = (row * 128 + cc * 2) ^ ((row & 7) << 4);
                *(bf16*)(Ah + off) = h;
                *(bf16*)(Al + off) = (bf16)(f - (float)h);
            }
        }
        // stage W
#pragma unroll
        for (int p = 0; p < 8; ++p) {
            int i  = p * 16 + (tid >> 4);
            int c4 = (tid & 15) * 4;
            f32x4 w4 = *(const f32x4*)(W + (size_t)i * NC + c0 + c4);
            bf16x4 hv, lv;
#pragma unroll
            for (int e = 0; e < 4; ++e) {
                bf16 h = (bf16)w4[e];
                hv[e] = h;
                lv[e] = (bf16)(w4[e] - (float)h);
            }
            int off = (i * 128 + c4 * 2) ^ ((i & 7) << 4);
            *(bf16x4*)(Wh + off) = hv;
            if (split) *(bf16x4*)(Wl + off) = lv;
        }
        __syncthreads();
        // MFMA: wave wv owns n-rows wv*16..+15, all 128 i
#pragma unroll
        for (int kk = 0; kk < 2; ++kk) {
            int row  = wv * 16 + lq;
            int koff = kk * 64 + lg * 16;
            int aoff = (row * 128 + koff) ^ ((row & 7) << 4);
            bf16x8 ah = *(const bf16x8*)(Ah + aoff);
            bf16x8 al = *(const bf16x8*)(Al + aoff);
#pragma unroll
            for (int j = 0; j < 8; ++j) {
                int ir   = j * 16 + lq;
                int woff = (ir * 128 + koff) ^ ((ir & 7) << 4);
                bf16x8 bh = *(const bf16x8*)(Wh + woff);
                acc[j] = MFMA16(ah, bh, acc[j]);
                if (split) {
                    bf16x8 bl = *(const bf16x8*)(Wl + woff);
                    acc[j] = MFMA16(ah, bl, acc[j]);
                    acc[j] = MFMA16(al, bh, acc[j]);
                }
            }
        }
    }

    if (pj == 2) {
        // transpose epilogue: acc -> T[i][n_local] in LDS -> vv[b][i][n] coalesced
        __syncthreads();
        char* T = lds;   // [128 i][64 n] bf16, row 128B, swizzled
#pragma unroll
        for (int j = 0; j < 8; ++j) {
            int i = j * 16 + lq;
            float bv = bias[i];
#pragma unroll
            for (int r = 0; r < 4; ++r) {
                int nl = wv * 16 + lg * 4 + r;
                int off = (i * 128 + nl * 2) ^ ((i & 7) << 4);
                *(bf16*)(T + off) = (bf16)(acc[j][r] + bv);
            }
        }
        __syncthreads();
#pragma unroll
        for (int p = 0; p < 4; ++p) {
            int i  = p * 32 + (tid >> 3);
            int sl = tid & 7;
            i32x4 t = *(const i32x4*)(T + ((i * 128 + sl * 16) ^ ((i & 7) << 4)));
            *(i32x4*)(vv + ((size_t)b * NCI + i) * NN + n0 + sl * 8) = t;
        }
    } else {
#pragma unroll
        for (int j = 0; j < 8; ++j) {
            int i = j * 16 + lq;
            float bv = bias[i];
#pragma unroll
            for (int r = 0; r < 4; ++r) {
                int q = n0 + wv * 16 + lg * 4 + r;
                size_t off = ((size_t)b * NN + q) * NCI + i;
                float val = acc[j][r] + bv;
                bf16 h = (bf16)val;
                bf16 l = (bf16)(val - (float)h);
                if (pj == 0) { qh[off] = h; ql[off] = l; }
                else         { kh[off] = h; kl[off] = l; }
            }
        }
    }
}

// ---------------------------------------------------------------------------
// Kernel 2: flash attention. 256 blocks x 256 thr (1 block/CU), 4 waves x 32 q
// (BQ=128). Swapped QK^T (S^T = K*Q), BK=64. Double-buffered K/V in LDS with
// register-staged prefetch: one __syncthreads per iteration.
// ---------------------------------------------------------------------------
__global__ __launch_bounds__(256, 1) void k_attn(
    const bf16* __restrict__ qh, const bf16* __restrict__ ql,
    const bf16* __restrict__ kh, const bf16* __restrict__ kl,
    const bf16* __restrict__ vt, bf16* __restrict__ y)
{
    const int bid = blockIdx.x;       // 0..255
    const int b   = bid & 7;          // batch == XCD (L2 colocation)
    const int qt  = bid >> 3;         // 0..31
    const int tid = threadIdx.x;
    const int wv  = tid >> 6;
    const int ln  = tid & 63;
    const int lg  = ln >> 4;          // 0..3
    const int lq  = ln & 15;
    const int n0  = qt * 128;

    // LDS: buf0 {KH,KL,VT} @0, buf1 @49152, P @98304 (4KB/wave) -> 112 KB
    __shared__ __attribute__((aligned(16))) char lds[114688];
    char* P = lds + 98304 + wv * 4096;   // [32 q][64 m] bf16, swizzled

    // staging lane constants
    const int smm = tid >> 4;   // K: row within 16-row group
    const int ssl = tid & 15;   // K: 16B unit within 256B row
    const int svd = tid >> 3;   // V: row within 32-row group
    const int svl = tid & 7;    // V: 16B unit within 128B row

    // ---- Q fragments (2 q-subtiles x 4 k-chunks), hi/lo, loop-invariant
    bf16x8 qhf[2][4], qlf[2][4];
#pragma unroll
    for (int q2 = 0; q2 < 2; ++q2) {
        int qrow = n0 + wv * 32 + q2 * 16 + lq;
        const bf16* bh = qh + ((size_t)b * NN + qrow) * NCI;
        const bf16* bl = ql + ((size_t)b * NN + qrow) * NCI;
#pragma unroll
        for (int kk = 0; kk < 4; ++kk) {
            qhf[q2][kk] = *(const bf16x8*)(bh + kk * 32 + lg * 8);
            qlf[q2][kk] = *(const bf16x8*)(bl + kk * 32 + lg * 8);
        }
    }

    f32x4 o[2][8];
#pragma unroll
    for (int q2 = 0; q2 < 2; ++q2)
#pragma unroll
        for (int j = 0; j < 8; ++j) o[q2][j] = f32x4{0.f, 0.f, 0.f, 0.f};
    float mrun[2] = {-1e30f, -1e30f};
    float lrun[2] = {0.f, 0.f};
    const float scale = 11.313708498984761f;   // sqrt(128)

    // ---- prologue: stage tile 0 into buf0
    {
#pragma unroll
        for (int p = 0; p < 4; ++p) {
            int mm = p * 16 + smm;
            size_t g = ((size_t)b * NN + mm) * NCI + ssl * 8;
            i32x4 h = *(const i32x4*)(kh + g);
            i32x4 l = *(const i32x4*)(kl + g);
            int off = (mm * 256 + ssl * 16) ^ ((mm & 7) << 4);
            *(i32x4*)(lds + off) = h;
            *(i32x4*)(lds + 16384 + off) = l;
        }
#pragma unroll
        for (int p = 0; p < 4; ++p) {
            int d = p * 32 + svd;
            size_t g = ((size_t)b * NCI + d) * NN + svl * 8;
            i32x4 v = *(const i32x4*)(vt + g);
            int off = (d * 128 + svl * 16) ^ ((d & 7) << 4);
            *(i32x4*)(lds + 32768 + off) = v;
        }
    }
    __syncthreads();

    for (int t = 0; t < 64; ++t) {
        const int cur = t & 1;
        char* KH  = lds + cur * 49152;
        char* KL  = KH + 16384;
        char* VT  = KH + 32768;
        char* KHn = lds + (cur ^ 1) * 49152;
        char* KLn = KHn + 16384;
        char* VTn = KHn + 32768;
        const int m0n = (t + 1) * 64;
        const bool pre = (t < 63);

        // ---- issue next K-tile loads (latency hides under QK^T)
        i32x4 rkh[4], rkl[4];
        if (pre) {
#pragma unroll
            for (int p = 0; p < 4; ++p) {
                size_t g = ((size_t)b * NN + m0n + p * 16 + smm) * NCI + ssl * 8;
                rkh[p] = *(const i32x4*)(kh + g);
                rkl[p] = *(const i32x4*)(kl + g);
            }
        }

        // ---- swapped QK^T: S^T[m][q], A=K (LDS), B=Q (regs), split 3-MFMA
        f32x4 s[4][2];
        __builtin_amdgcn_s_setprio(1);
#pragma unroll
        for (int jm = 0; jm < 4; ++jm) {
            s[jm][0] = f32x4{0.f, 0.f, 0.f, 0.f};
            s[jm][1] = f32x4{0.f, 0.f, 0.f, 0.f};
            const int mrow = jm * 16 + lq;
            const int sw = (mrow & 7) << 4;
#pragma unroll
            for (int kk = 0; kk < 4; ++kk) {
                int aoff = (mrow * 256 + kk * 64 + lg * 16) ^ sw;
                bf16x8 ah = *(const bf16x8*)(KH + aoff);
                bf16x8 al = *(const bf16x8*)(KL + aoff);
                s[jm][0] = MFMA16(ah, qhf[0][kk], s[jm][0]);
                s[jm][1] = MFMA16(ah, qhf[1][kk], s[jm][1]);
                s[jm][0] = MFMA16(al, qhf[0][kk], s[jm][0]);
                s[jm][1] = MFMA16(al, qhf[1][kk], s[jm][1]);
                s[jm][0] = MFMA16(ah, qlf[0][kk], s[jm][0]);
                s[jm][1] = MFMA16(ah, qlf[1][kk], s[jm][1]);
            }
        }
        __builtin_amdgcn_s_setprio(0);

        // ---- write next K into other buffer; issue next V loads
        i32x4 rv[4];
        if (pre) {
#pragma unroll
            for (int p = 0; p < 4; ++p) {
                int mm = p * 16 + smm;
                int off = (mm * 256 + ssl * 16) ^ ((mm & 7) << 4);
                *(i32x4*)(KHn + off) = rkh[p];
                *(i32x4*)(KLn + off) = rkl[p];
            }
#pragma unroll
            for (int p = 0; p < 4; ++p) {
                size_t g = ((size_t)b * NCI + p * 32 + svd) * NN + m0n + svl * 8;
                rv[p] = *(const i32x4*)(vt + g);
            }
        }

        // ---- online softmax (lane owns columns q2*16+lq; butterfly over lg)
        float tm[2];
        tm[0] = s[0][0][0];
        tm[1] = s[0][1][0];
#pragma unroll
        for (int jm = 0; jm < 4; ++jm)
#pragma unroll
            for (int r = 0; r < 4; ++r) {
                tm[0] = fmaxf(tm[0], s[jm][0][r]);
                tm[1] = fmaxf(tm[1], s[jm][1][r]);
            }
#pragma unroll
        for (int q2 = 0; q2 < 2; ++q2) {
            tm[q2] = fmaxf(tm[q2], __shfl_xor(tm[q2], 16));
            tm[q2] = fmaxf(tm[q2], __shfl_xor(tm[q2], 32));
        }
        float alpha[2], psum[2];
#pragma unroll
        for (int q2 = 0; q2 < 2; ++q2) {
            float mnew = fmaxf(mrun[q2], tm[q2] * scale);
            alpha[q2] = __expf(mrun[q2] - mnew);
            mrun[q2] = mnew;
            psum[q2] = 0.f;
        }
        // exp + pack P[q][m] (bf16x4 = 4 consecutive m)
#pragma unroll
        for (int jm = 0; jm < 4; ++jm)
#pragma unroll
            for (int q2 = 0; q2 < 2; ++q2) {
                bf16x4 pk;
#pragma unroll
                for (int r = 0; r < 4; ++r) {
                    float e = __expf(s[jm][q2][r] * scale - mrun[q2]);
                    psum[q2] += e;
                    pk[r] = (bf16)e;
                }
                int row = q2 * 16 + lq;
                int off = (row * 128 + (jm * 16 + lg * 4) * 2) ^ ((lq & 7) << 4);
                *(bf16x4*)(P + off) = pk;
            }
#pragma unroll
        for (int q2 = 0; q2 < 2; ++q2) {
            psum[q2] += __shfl_xor(psum[q2], 16);
            psum[q2] += __shfl_xor(psum[q2], 32);
            lrun[q2] = lrun[q2] * alpha[q2] + psum[q2];
        }

        // ---- rescale O (alpha for row-q lives at column-lane lg*4+r)
        float av0[4], av1[4];
#pragma unroll
        for (int r = 0; r < 4; ++r) {
            av0[r] = __shfl(alpha[0], lg * 4 + r);
            av1[r] = __shfl(alpha[1], lg * 4 + r);
        }
#pragma unroll
        for (int j = 0; j < 8; ++j)
#pragma unroll
            for (int r = 0; r < 4; ++r) {
                o[0][j][r] *= av0[r];
                o[1][j][r] *= av1[r];
            }

        // ---- PV: O[q][d] += P[q][m] * V[m][d]
        bf16x8 pa[2][2];
#pragma unroll
        for (int q2 = 0; q2 < 2; ++q2)
#pragma unroll
            for (int tt = 0; tt < 2; ++tt) {
                int row = q2 * 16 + lq;
                pa[q2][tt] = *(const bf16x8*)(P + ((row * 128 + tt * 64 + lg * 16) ^ ((lq & 7) << 4)));
            }
        __builtin_amdgcn_s_setprio(1);
#pragma unroll
        for (int j = 0; j < 8; ++j) {
            int d = j * 16 + lq;
            int swv = (lq & 7) << 4;   // (d & 7) == (lq & 7)
#pragma unroll
            for (int tt = 0; tt < 2; ++tt) {
                bf16x8 bv = *(const bf16x8*)(VT + ((d * 128 + tt * 64 + lg * 16) ^ swv));
                o[0][j] = MFMA16(pa[0][tt], bv, o[0][j]);
                o[1][j] = MFMA16(pa[1][tt], bv, o[1][j]);
            }
        }
        __builtin_amdgcn_s_setprio(0);

        // ---- write next V into other buffer
        if (pre) {
#pragma unroll
            for (int p = 0; p < 4; ++p) {
                int d = p * 32 + svd;
                int off = (d * 128 + svl * 16) ^ ((d & 7) << 4);
                *(i32x4*)(VTn + off) = rv[p];
            }
        }
        __syncthreads();
    }

    // ---- epilogue: y = O / l
    float rl0[4], rl1[4];
#pragma unroll
    for (int r = 0; r < 4; ++r) {
        rl0[r] = 1.f / __shfl(lrun[0], lg * 4 + r);
        rl1[r] = 1.f / __shfl(lrun[1], lg * 4 + r);
    }
#pragma unroll
    for (int j = 0; j < 8; ++j) {
        int d = j * 16 + lq;
#pragma unroll
        for (int r = 0; r < 4; ++r) {
            int q0 = n0 + wv * 32 + lg * 4 + r;
            y[((size_t)b * NN + q0) * NCI + d]      = (bf16)(o[0][j][r] * rl0[r]);
            y[((size_t)b * NN + q0 + 16) * NCI + d] = (bf16)(o[1][j][r] * rl1[r]);
        }
    }
}

// ---------------------------------------------------------------------------
// Kernel 3: out[b,c,n] = x[b,c,n] + sum_i y[b,n,i]*w_out[c,i] + b_out[c]
// ---------------------------------------------------------------------------
__global__ __launch_bounds__(256) void k_out(
    const bf16* __restrict__ y, const float* __restrict__ x,
    const float* __restrict__ w_out, const float* __restrict__ b_out,
    float* __restrict__ out)
{
    const int nt  = blockIdx.x;
    const int b   = blockIdx.y;
    const int tid = threadIdx.x;
    const int wv  = tid >> 6;
    const int ln  = tid & 63;
    const int lg  = ln >> 4;
    const int lq  = ln & 15;
    const int n0  = nt * 64;

    __shared__ char Y[16384];   // [64 n][128 i] bf16, swizzled
#pragma unroll
    for (int p = 0; p < 4; ++p) {
        int nn = p * 16 + (tid >> 4);
        int d0 = (tid & 15) * 8;
        i32x4 t = *(const i32x4*)(y + ((size_t)b * NN + n0 + nn) * NCI + d0);
        *(i32x4*)(Y + ((nn * 256 + d0 * 2) ^ ((nn & 7) << 4))) = t;
    }
    __syncthreads();

    bf16x8 af[4];
    {
        int row = wv * 16 + lq;
#pragma unroll
        for (int kk = 0; kk < 4; ++kk) {
            int koff = kk * 64 + lg * 16;
            af[kk] = *(const bf16x8*)(Y + ((row * 256 + koff) ^ ((row & 7) << 4)));
        }
    }

    f32x4 acc[16];
#pragma unroll
    for (int j = 0; j < 16; ++j) acc[j] = f32x4{0.f, 0.f, 0.f, 0.f};

#pragma unroll
    for (int j = 0; j < 16; ++j) {
        int c = j * 16 + lq;
#pragma unroll
        for (int kk = 0; kk < 4; ++kk) {
            int i0 = kk * 32 + lg * 8;
            f32x4 wa = *(const f32x4*)(w_out + (size_t)c * NCI + i0);
            f32x4 wb = *(const f32x4*)(w_out + (size_t)c * NCI + i0 + 4);
            bf16x8 bw;
#pragma unroll
            for (int e = 0; e < 4; ++e) { bw[e] = (bf16)wa[e]; bw[e + 4] = (bf16)wb[e]; }
            acc[j] = MFMA16(af[kk], bw, acc[j]);
        }
    }

#pragma unroll
    for (int j = 0; j < 16; ++j) {
        int c = j * 16 + lq;
        int nb = n0 + wv * 16 + lg * 4;
        size_t off = ((size_t)b * NC + c) * (size_t)NN + nb;
        f32x4 xv = *(const f32x4*)(x + off);
        float bo = b_out[c];
        f32x4 r;
#pragma unroll
        for (int t = 0; t < 4; ++t) r[t] = acc[j][t] + xv[t] + bo;
        *(f32x4*)(out + off) = r;
    }
}

// ---------------------------------------------------------------------------
extern "C" void kernel_launch(void* const* d_in, const int* in_sizes, int n_in,
                              void* d_out, int out_size, void* d_ws, size_t ws_size,
                              hipStream_t stream)
{
    (void)in_sizes; (void)n_in; (void)out_size; (void)ws_size;
    const float* x  = (const float*)d_in[0];
    const float* wg = (const float*)d_in[1];
    const float* bg = (const float*)d_in[2];
    const float* wt = (const float*)d_in[3];
    const float* bt = (const float*)d_in[4];
    const float* wp = (const float*)d_in[5];
    const float* bp = (const float*)d_in[6];
    const float* wo = (const float*)d_in[7];
    const float* bo = (const float*)d_in[8];
    float* out = (float*)d_out;

    char* ws = (char*)d_ws;
    bf16* qh = (bf16*)(ws);
    bf16* ql = (bf16*)(ws + NEL * 2);
    bf16* kh = (bf16*)(ws + NEL * 4);
    bf16* kl = (bf16*)(ws + NEL * 6);
    bf16* vv = (bf16*)(ws + NEL * 8);   // transposed: [b][ci][n]
    bf16* y  = qh;  // reuse: attn block reads its own Q rows before writing them

    k_proj<<<dim3(64, 3, 8), 256, 0, stream>>>(x, wt, bt, wp, bp, wg, bg,
                                               qh, ql, kh, kl, vv);
    k_attn<<<dim3(256), 256, 0, stream>>>(qh, ql, kh, kl, vv, y);
    k_out<<<dim3(64, 8), 256, 0, stream>>>(y, x, wo, bo, out);
}